// Round 3
// baseline (630.083 us; speedup 1.0000x reference)
//
#include <hip/hip_runtime.h>

#define TPB 256

// One conv step inside LDS. Valid input region rows/cols [K, S0-K);
// output region [K+1, S0-K-1), written to nxt. 4-row blocking per thread:
// 18 LDS reads per 4 outputs instead of 36.
// Outputs whose GLOBAL image coordinate is outside [0,N) are forced to 0 —
// this reproduces the reference's zero-padding of every intermediate conv
// output at image boundaries (interior tile halos are true conv values).
template<int S0, int LDW, int K>
__device__ __forceinline__ void conv_step(const float* __restrict__ cur,
                                          float* __restrict__ nxt,
                                          const float (&W)[9], int tid,
                                          int gy0, int gx0, int N)
{
    constexpr int S  = S0 - 2 * (K + 1);   // output region size this step
    constexpr int RB = (S + 3) / 4;        // 4-row blocks
    for (int idx = tid; idx < RB * S; idx += TPB) {
        const int cr = idx % S;            // compile-time S -> magic mul
        const int rb = idx / S;
        const int r0 = K + 1 + rb * 4;
        const int c  = K + 1 + cr;
        const int gc = gx0 + c;
        const bool colOK = (gc >= 0) && (gc < N);
        float acc[4] = {0.f, 0.f, 0.f, 0.f};
        #pragma unroll
        for (int i = 0; i < 6; ++i) {
            int rr = r0 - 1 + i;
            if (rr > S0 - 1) rr = S0 - 1;  // clamp: clamped rows never feed valid outputs
            const float* p = &cur[rr * LDW + (c - 1)];
            const float x0 = p[0], x1 = p[1], x2 = p[2];
            #pragma unroll
            for (int j = 0; j < 4; ++j) {
                if (j <= i && i <= j + 2) {      // folds at compile time
                    const int t = i - j;         // weight row
                    acc[j] += x0 * W[t * 3 + 0] + x1 * W[t * 3 + 1] + x2 * W[t * 3 + 2];
                }
            }
        }
        #pragma unroll
        for (int j = 0; j < 4; ++j) {
            const int r = r0 + j;
            if (r < S0 - K - 1) {
                const int gr = gy0 + r;
                const bool ok = colOK && (gr >= 0) && (gr < N);
                nxt[r * LDW + c] = ok ? acc[j] : 0.f;
            }
        }
    }
}

// Fused stage: NC 3x3 convs (SAME, zero pad) + 2x2 maxpool.
// Block computes a 32x32 pooled tile = 64x64 conv region.
template<int NC>
__global__ __launch_bounds__(TPB) void stage_kernel(
    const float* __restrict__ in, int N, int NO,
    const float* __restrict__ w0p, const float* __restrict__ w1p,
    const float* __restrict__ w2p,
    float* __restrict__ out)
{
    constexpr int CT  = 64;            // conv-output tile
    constexpr int S0  = CT + 2 * NC;   // staged input tile (with halo)
    constexpr int LDW = S0 + 1;        // odd stride: no bank conflicts
    __shared__ float bufA[S0 * LDW];
    __shared__ float bufB[S0 * LDW];

    const int tid = threadIdx.x;
    const int px0 = blockIdx.x * 32;   // pooled-coords tile origin
    const int py0 = blockIdx.y * 32;
    const int cx0 = px0 * 2 - NC;      // input coord of buffer (0,0)
    const int cy0 = py0 * 2 - NC;

    float W0[9], W1[9], W2[9];
    #pragma unroll
    for (int i = 0; i < 9; ++i) { W0[i] = w0p[i]; W1[i] = w1p[i]; }
    if constexpr (NC == 3) {
        #pragma unroll
        for (int i = 0; i < 9; ++i) W2[i] = w2p[i];
    } else {
        (void)w2p;
        #pragma unroll
        for (int i = 0; i < 9; ++i) W2[i] = 0.f;
    }

    // Stage input tile into LDS, zero outside the image (== SAME padding).
    for (int idx = tid; idx < S0 * S0; idx += TPB) {
        const int r = idx / S0, c = idx % S0;
        const int gy = cy0 + r, gx = cx0 + c;
        float v = 0.f;
        if (gy >= 0 && gy < N && gx >= 0 && gx < N)
            v = in[(size_t)gy * N + gx];
        bufA[r * LDW + c] = v;
    }
    __syncthreads();

    conv_step<S0, LDW, 0>(bufA, bufB, W0, tid, cy0, cx0, N);
    __syncthreads();
    conv_step<S0, LDW, 1>(bufB, bufA, W1, tid, cy0, cx0, N);
    __syncthreads();
    const float* fin;
    if constexpr (NC == 3) {
        conv_step<S0, LDW, 2>(bufA, bufB, W2, tid, cy0, cx0, N);
        __syncthreads();
        fin = bufB;
    } else {
        fin = bufA;
    }

    // 2x2 max pool over conv region rows/cols [NC, NC+64)
    for (int idx = tid; idx < 32 * 32; idx += TPB) {
        const int py = idx >> 5, px = idx & 31;
        const int r = NC + 2 * py, c = NC + 2 * px;
        const float m0 = fmaxf(fin[r * LDW + c],       fin[r * LDW + c + 1]);
        const float m1 = fmaxf(fin[(r + 1) * LDW + c], fin[(r + 1) * LDW + c + 1]);
        out[(size_t)(py0 + py) * NO + (px0 + px)] = fmaxf(m0, m1);
    }
}

extern "C" void kernel_launch(void* const* d_in, const int* in_sizes, int n_in,
                              void* d_out, int out_size, void* d_ws, size_t ws_size,
                              hipStream_t stream) {
    const float* x = (const float*)d_in[0];
    const float* w[10];
    for (int i = 0; i < 10; ++i) w[i] = (const float*)d_in[1 + i];
    float* out = (float*)d_out;

    // Workspace layout: t1 (4096^2) | t2 (2048^2) | t3 (1024^2)  = 84 MB
    float* t1 = (float*)d_ws;
    float* t2 = t1 + (size_t)4096 * 4096;
    float* t3 = t2 + (size_t)2048 * 2048;

    dim3 b(TPB);
    // stage 1: x(8192^2) -> conv w1,w2 -> pool -> t1(4096^2)
    stage_kernel<2><<<dim3(128, 128), b, 0, stream>>>(x, 8192, 4096, w[0], w[1], nullptr, t1);
    // stage 2: t1 -> conv w3,w4 -> pool -> t2(2048^2)
    stage_kernel<2><<<dim3(64, 64), b, 0, stream>>>(t1, 4096, 2048, w[2], w[3], nullptr, t2);
    // stage 3: t2 -> conv w5,w6,w7 -> pool -> t3(1024^2)
    stage_kernel<3><<<dim3(32, 32), b, 0, stream>>>(t2, 2048, 1024, w[4], w[5], w[6], t3);
    // stage 4: t3 -> conv w8,w9,w10 -> pool -> out(512^2)
    stage_kernel<3><<<dim3(16, 16), b, 0, stream>>>(t3, 1024, 512, w[7], w[8], w[9], out);
}